// Round 7
// baseline (296.171 us; speedup 1.0000x reference)
//
#include <hip/hip_runtime.h>
#include <hip/hip_bf16.h>

typedef unsigned short ushort_t;
typedef __attribute__((ext_vector_type(8))) short bf16x8;
typedef __attribute__((ext_vector_type(4))) float f32x4;

#define B_SZ 4096
#define N_SZ 8
#define D_SZ 256
#define FF_SZ 2048
#define M_SZ (B_SZ * N_SZ)   // 32768
#define WELEM (D_SZ * D_SZ * N_SZ)  // 524288

__device__ inline float b2f(ushort_t u) {
    union { unsigned int i; float f; } t; t.i = ((unsigned int)u) << 16; return t.f;
}
__device__ inline ushort_t f2b(float f) {
    union { unsigned int i; float f; } t; t.f = f;
    unsigned int i = t.i;
    unsigned int r = (i + 0x7fffu + ((i >> 16) & 1u)) >> 16;
    return (ushort_t)r;
}

// async global->LDS, 16B per lane; LDS dest must be wave-uniform base + lane*16
__device__ inline void gl2lds16(const ushort_t* g, ushort_t* l) {
    __builtin_amdgcn_global_load_lds((const __attribute__((address_space(1))) void*)g,
                                     (__attribute__((address_space(3))) void*)l, 16, 0, 0);
}

// ---------------- convert/repack all weights f32 -> bf16
// blocks 0..255  : LDS-transpose repack of w_in/w_out -> bt  (bt[d2*2048+s*256+d1] = w[d1*2048+d2*8+s])
// blocks 256..767: straight convert W1 / W2 (already [n][k])
__global__ __launch_bounds__(256) void convert_weights(const float* __restrict__ w_in,
                                                       const float* __restrict__ w_out,
                                                       const float* __restrict__ W1,
                                                       const float* __restrict__ W2,
                                                       ushort_t* __restrict__ bt_in,
                                                       ushort_t* __restrict__ bt_out,
                                                       ushort_t* __restrict__ W1b,
                                                       ushort_t* __restrict__ W2b) {
    __shared__ float tile[64][65];
    const int bid = blockIdx.x;
    const int t = threadIdx.x;
    if (bid < 256) {
        const float* w = (bid < 128) ? w_in : w_out;
        ushort_t* bt = (bid < 128) ? bt_in : bt_out;
        const int id = bid & 127;
        const int d10 = (id >> 5) * 64;   // 0..3  -> d1 tile
        const int j0  = (id & 31) * 64;   // 0..31 -> j = d2*8+s tile
#pragma unroll
        for (int it = 0; it < 16; ++it) {
            const int d1l = it * 4 + (t >> 6);
            const int jl = t & 63;
            tile[d1l][jl] = w[(size_t)(d10 + d1l) * 2048 + j0 + jl];
        }
        __syncthreads();
#pragma unroll
        for (int it = 0; it < 16; ++it) {
            const int jl = it * 4 + (t >> 6);
            const int d1l = t & 63;
            const int j = j0 + jl;
            bt[(size_t)(j >> 3) * 2048 + (j & 7) * 256 + d10 + d1l] = f2b(tile[d1l][jl]);
        }
    } else {
        const int id = bid - 256;          // 0..511
        const float* w = (id < 256) ? W1 : W2;
        ushort_t* o = (id < 256) ? W1b : W2b;
        const size_t base = (size_t)(id & 255) * 2048 + t * 8;
        const float4 a = *(const float4*)&w[base];
        const float4 b = *(const float4*)&w[base + 4];
        *(ushort4*)&o[base]     = make_ushort4(f2b(a.x), f2b(a.y), f2b(a.z), f2b(a.w));
        *(ushort4*)&o[base + 4] = make_ushort4(f2b(b.x), f2b(b.y), f2b(b.z), f2b(b.w));
    }
}

// ---------------- LN1: one WAVE per row of 256, float4 loads, shuffle-only reduce
__global__ __launch_bounds__(256) void ln_fast(const float* __restrict__ xin,
                                               const float* __restrict__ gam,
                                               const float* __restrict__ bet,
                                               ushort_t* __restrict__ out) {
    const int wave = threadIdx.x >> 6;
    const int lane = threadIdx.x & 63;
    const size_t row = (size_t)blockIdx.x * 4 + wave;
    const float4 v = *(const float4*)&xin[row * 256 + lane * 4];
    float s = v.x + v.y + v.z + v.w;
    float q = v.x * v.x + v.y * v.y + v.z * v.z + v.w * v.w;
#pragma unroll
    for (int off = 1; off < 64; off <<= 1) {
        s += __shfl_xor(s, off, 64);
        q += __shfl_xor(q, off, 64);
    }
    const float mu = s * (1.0f / 256.0f);
    const float var = q * (1.0f / 256.0f) - mu * mu;
    const float rs = rsqrtf(var + 1e-5f);
    const float4 g = *(const float4*)&gam[lane * 4];
    const float4 b = *(const float4*)&bet[lane * 4];
    ushort4 o;
    o.x = f2b((v.x - mu) * rs * g.x + b.x);
    o.y = f2b((v.y - mu) * rs * g.y + b.y);
    o.z = f2b((v.z - mu) * rs * g.z + b.z);
    o.w = f2b((v.w - mu) * rs * g.w + b.w);
    *(ushort4*)&out[row * 256 + lane * 4] = o;
}

// ---------------- unified GEMM: C[128 x 256] tile per block, 512 threads (8 waves, 2x4)
// BK=64, XOR-swizzled LDS chunks (conflict-free ds_read_b128), global_load_lds staging.
// MODE 0: TT   (A = gathered xn, K=2048, grid (1,256); epi: +ent, fused LN2 -> yn bf16, xb bf16)
// MODE 1: FF1  (A = yn, K=256, grid (8,256);  epi: +bias1, relu -> h1 bf16)
// MODE 2: FF2  (A = h1, K=2048, grid (1,256); epi: +bias2 + b2f(xb) -> out f32)
template <int MODE, int K>
__global__ __launch_bounds__(512) void gemm5(const ushort_t* __restrict__ A,
                                             const ushort_t* __restrict__ Bt0,
                                             const ushort_t* __restrict__ Bt1,
                                             const float* __restrict__ biasf,   // g2 | bias1 | bias2
                                             const float* __restrict__ be2f,    // MODE0 only
                                             const float* __restrict__ entf,    // MODE0 only
                                             const ushort_t* __restrict__ resb, // MODE2 only (xb)
                                             float* __restrict__ outf,
                                             ushort_t* __restrict__ outb,
                                             ushort_t* __restrict__ outb2) {
    __shared__ __attribute__((aligned(16))) ushort_t As[128 * 64];   // 16 KB
    __shared__ __attribute__((aligned(16))) ushort_t Bs[256 * 64];   // 32 KB
    __shared__ float red_s[128 * 4];                                 // MODE0
    __shared__ float red_q[128 * 4];

    const int t = threadIdx.x;
    const int m0 = blockIdx.y * 128;
    const int n0 = blockIdx.x * 256;       // 0 unless MODE1
    const int lane = t & 63;
    const int wave = t >> 6;
    const int wr = wave & 1, wc = wave >> 1;   // 2 x 4 wave grid
    const int l16 = lane & 15, quad = lane >> 4;
    const int tr = t >> 3;                 // staging row-within-part 0..63
    const int csw = (((t & 7) ^ (tr & 7)) << 3);   // swizzled chunk offset (elems)

    const ushort_t* Bt = (MODE == 0 && m0 >= M_SZ / 2) ? Bt1 : Bt0;

    f32x4 acc[4][4];
#pragma unroll
    for (int i = 0; i < 4; i++)
#pragma unroll
        for (int j = 0; j < 4; j++) acc[i][j] = (f32x4)(0.0f);

    for (int kt = 0; kt < K / 64; ++kt) {
        const int kg = kt * 64;
        __syncthreads();                   // previous iter's ds_reads complete
#pragma unroll
        for (int p = 0; p < 2; ++p) {      // A: 128 rows
            const int row = p * 64 + tr;
            const ushort_t* gA;
            if (MODE == 0) {
                const int mrow = m0 + row;
                const int kcol = kg + csw;             // stays within one 256-seg
                const int s = kcol >> 8;
                gA = A + (size_t)((mrow & ~7) + (((mrow & 7) - s) & 7)) * 256 + (kcol & 255);
            } else {
                gA = A + (size_t)(m0 + row) * K + kg + csw;
            }
            gl2lds16(gA, As + p * 4096 + t * 8);
        }
#pragma unroll
        for (int p = 0; p < 4; ++p) {      // B: 256 rows
            const int row = p * 64 + tr;
            gl2lds16(Bt + (size_t)(n0 + row) * K + kg + csw, Bs + p * 4096 + t * 8);
        }
        __syncthreads();                   // staging complete

#pragma unroll
        for (int kk = 0; kk < 2; ++kk) {
            const int ac = ((((kk << 2) | quad) ^ (l16 & 7)) << 3);
            bf16x8 af[4], bfv[4];
#pragma unroll
            for (int i = 0; i < 4; i++) af[i]  = *(const bf16x8*)&As[(wr * 64 + i * 16 + l16) * 64 + ac];
#pragma unroll
            for (int j = 0; j < 4; j++) bfv[j] = *(const bf16x8*)&Bs[(wc * 64 + j * 16 + l16) * 64 + ac];
#pragma unroll
            for (int i = 0; i < 4; i++)
#pragma unroll
                for (int j = 0; j < 4; j++)
                    acc[i][j] = __builtin_amdgcn_mfma_f32_16x16x32_bf16(af[i], bfv[j], acc[i][j], 0, 0, 0);
        }
    }

    // ---- epilogue
    if (MODE == 0) {
        int c[4];
#pragma unroll
        for (int j = 0; j < 4; j++) c[j] = wc * 64 + j * 16 + l16;
#pragma unroll
        for (int i = 0; i < 4; i++) {
#pragma unroll
            for (int r = 0; r < 4; r++) {
                const int rl = wr * 64 + i * 16 + quad * 4 + r;   // 0..127
                const size_t grow = (size_t)(m0 + rl) * 256;
                float s = 0.0f, q = 0.0f;
#pragma unroll
                for (int j = 0; j < 4; j++) {
                    float v = acc[i][j][r] + entf[grow + c[j]];
                    acc[i][j][r] = v;
                    s += v;
                    q += v * v;
                }
#pragma unroll
                for (int off = 1; off < 16; off <<= 1) {
                    s += __shfl_xor(s, off, 64);
                    q += __shfl_xor(q, off, 64);
                }
                if (l16 == 0) { red_s[rl * 4 + wc] = s; red_q[rl * 4 + wc] = q; }
            }
        }
        __syncthreads();
#pragma unroll
        for (int i = 0; i < 4; i++) {
#pragma unroll
            for (int r = 0; r < 4; r++) {
                const int rl = wr * 64 + i * 16 + quad * 4 + r;
                const size_t grow = (size_t)(m0 + rl) * 256;
                const float4 ss = *(const float4*)&red_s[rl * 4];
                const float4 qq = *(const float4*)&red_q[rl * 4];
                const float S = ss.x + ss.y + ss.z + ss.w;
                const float Q = qq.x + qq.y + qq.z + qq.w;
                const float mu = S * (1.0f / 256.0f);
                const float var = Q * (1.0f / 256.0f) - mu * mu;
                const float rs = rsqrtf(var + 1e-5f);
#pragma unroll
                for (int j = 0; j < 4; j++) {
                    const float v = acc[i][j][r];
                    outb[grow + c[j]]  = f2b((v - mu) * rs * biasf[c[j]] + be2f[c[j]]);
                    outb2[grow + c[j]] = f2b(v);
                }
            }
        }
    } else {
#pragma unroll
        for (int i = 0; i < 4; i++) {
#pragma unroll
            for (int j = 0; j < 4; j++) {
                const int r0 = m0 + wr * 64 + i * 16 + quad * 4;
                const int c = n0 + wc * 64 + j * 16 + l16;
#pragma unroll
                for (int r = 0; r < 4; r++) {
                    float v = acc[i][j][r];
                    if (MODE == 1) {
                        const size_t o = (size_t)(r0 + r) * 2048 + c;
                        v += biasf[c];
                        v = v > 0.0f ? v : 0.0f;
                        outb[o] = f2b(v);
                    } else {
                        const size_t o = (size_t)(r0 + r) * 256 + c;
                        v += biasf[c] + b2f(resb[o]);
                        outf[o] = v;
                    }
                }
            }
        }
    }
}

extern "C" void kernel_launch(void* const* d_in, const int* in_sizes, int n_in,
                              void* d_out, int out_size, void* d_ws, size_t ws_size,
                              hipStream_t stream) {
    const float* ent   = (const float*)d_in[0];
    const float* w_in  = (const float*)d_in[1];
    const float* w_out = (const float*)d_in[2];
    const float* W1    = (const float*)d_in[3];
    const float* bias1 = (const float*)d_in[4];
    const float* W2    = (const float*)d_in[5];
    const float* bias2 = (const float*)d_in[6];
    const float* g1    = (const float*)d_in[7];
    const float* be1   = (const float*)d_in[8];
    const float* g2    = (const float*)d_in[9];
    const float* be2   = (const float*)d_in[10];
    float* out = (float*)d_out;

    char* ws = (char*)d_ws;
    ushort_t* xn     = (ushort_t*)ws;
    ushort_t* yn     = (ushort_t*)(ws + 16777216);
    ushort_t* xb     = (ushort_t*)(ws + 2 * 16777216);
    ushort_t* h1     = (ushort_t*)(ws + 3 * 16777216);
    ushort_t* bt_in  = (ushort_t*)(ws + 3 * 16777216 + 134217728);
    ushort_t* bt_out = bt_in + WELEM;
    ushort_t* W1b    = bt_out + WELEM;
    ushort_t* W2b    = W1b + WELEM;

    const ushort_t* null_u = nullptr;
    const float*    null_f = nullptr;
    ushort_t*       null_ou = nullptr;
    float*          null_of = nullptr;

    // 1) convert + repack all weights to bf16 (coalesced via LDS transpose)
    convert_weights<<<dim3(768), dim3(256), 0, stream>>>(w_in, w_out, W1, W2,
                                                         bt_in, bt_out, W1b, W2b);
    // 2) LN1: ent -> xn (bf16)
    ln_fast<<<dim3(M_SZ / 4), dim3(256), 0, stream>>>(ent, g1, be1, xn);
    // 3) TT gemm + fused LN2: yn, xb
    gemm5<0, 2048><<<dim3(1, 256), dim3(512), 0, stream>>>(
        xn, bt_in, bt_out, g2, be2, ent, null_u, null_of, yn, xb);
    // 4) FF1: h1 = relu(yn @ W1b^T + bias1)
    gemm5<1, 256><<<dim3(8, 256), dim3(512), 0, stream>>>(
        yn, W1b, null_u, bias1, null_f, null_f, null_u, null_of, h1, null_ou);
    // 5) FF2: out = xb + h1 @ W2b^T + bias2
    gemm5<2, 2048><<<dim3(1, 256), dim3(512), 0, stream>>>(
        h1, W2b, null_u, bias2, null_f, null_f, xb, out, null_ou, null_ou);
}

// Round 9
// 261.308 us; speedup vs baseline: 1.1334x; 1.1334x over previous
//
#include <hip/hip_runtime.h>
#include <hip/hip_bf16.h>

typedef unsigned short ushort_t;
typedef __attribute__((ext_vector_type(8))) short bf16x8;
typedef __attribute__((ext_vector_type(4))) float f32x4;

#define B_SZ 4096
#define N_SZ 8
#define D_SZ 256
#define FF_SZ 2048
#define M_SZ (B_SZ * N_SZ)   // 32768
#define WELEM (D_SZ * D_SZ * N_SZ)  // 524288

__device__ inline float b2f(ushort_t u) {
    union { unsigned int i; float f; } t; t.i = ((unsigned int)u) << 16; return t.f;
}
__device__ inline ushort_t f2b(float f) {
    union { unsigned int i; float f; } t; t.f = f;
    unsigned int i = t.i;
    unsigned int r = (i + 0x7fffu + ((i >> 16) & 1u)) >> 16;
    return (ushort_t)r;
}

// async global->LDS, 16B per lane; LDS dest must be wave-uniform base + lane*16
__device__ inline void gl2lds16(const ushort_t* g, ushort_t* l) {
    __builtin_amdgcn_global_load_lds((const __attribute__((address_space(1))) void*)g,
                                     (__attribute__((address_space(3))) void*)l, 16, 0, 0);
}

// ---------------- convert/repack all weights f32 -> bf16
__global__ __launch_bounds__(256) void convert_weights(const float* __restrict__ w_in,
                                                       const float* __restrict__ w_out,
                                                       const float* __restrict__ W1,
                                                       const float* __restrict__ W2,
                                                       ushort_t* __restrict__ bt_in,
                                                       ushort_t* __restrict__ bt_out,
                                                       ushort_t* __restrict__ W1b,
                                                       ushort_t* __restrict__ W2b) {
    __shared__ float tile[64][65];
    const int bid = blockIdx.x;
    const int t = threadIdx.x;
    if (bid < 256) {
        const float* w = (bid < 128) ? w_in : w_out;
        ushort_t* bt = (bid < 128) ? bt_in : bt_out;
        const int id = bid & 127;
        const int d10 = (id >> 5) * 64;
        const int j0  = (id & 31) * 64;
#pragma unroll
        for (int it = 0; it < 16; ++it) {
            const int d1l = it * 4 + (t >> 6);
            const int jl = t & 63;
            tile[d1l][jl] = w[(size_t)(d10 + d1l) * 2048 + j0 + jl];
        }
        __syncthreads();
#pragma unroll
        for (int it = 0; it < 16; ++it) {
            const int jl = it * 4 + (t >> 6);
            const int d1l = t & 63;
            const int j = j0 + jl;
            bt[(size_t)(j >> 3) * 2048 + (j & 7) * 256 + d10 + d1l] = f2b(tile[d1l][jl]);
        }
    } else {
        const int id = bid - 256;
        const float* w = (id < 256) ? W1 : W2;
        ushort_t* o = (id < 256) ? W1b : W2b;
        const size_t base = (size_t)(id & 255) * 2048 + t * 8;
        const float4 a = *(const float4*)&w[base];
        const float4 b = *(const float4*)&w[base + 4];
        *(ushort4*)&o[base]     = make_ushort4(f2b(a.x), f2b(a.y), f2b(a.z), f2b(a.w));
        *(ushort4*)&o[base + 4] = make_ushort4(f2b(b.x), f2b(b.y), f2b(b.z), f2b(b.w));
    }
}

// ---------------- LN1: one WAVE per row of 256
__global__ __launch_bounds__(256) void ln_fast(const float* __restrict__ xin,
                                               const float* __restrict__ gam,
                                               const float* __restrict__ bet,
                                               ushort_t* __restrict__ out) {
    const int wave = threadIdx.x >> 6;
    const int lane = threadIdx.x & 63;
    const size_t row = (size_t)blockIdx.x * 4 + wave;
    const float4 v = *(const float4*)&xin[row * 256 + lane * 4];
    float s = v.x + v.y + v.z + v.w;
    float q = v.x * v.x + v.y * v.y + v.z * v.z + v.w * v.w;
#pragma unroll
    for (int off = 1; off < 64; off <<= 1) {
        s += __shfl_xor(s, off, 64);
        q += __shfl_xor(q, off, 64);
    }
    const float mu = s * (1.0f / 256.0f);
    const float var = q * (1.0f / 256.0f) - mu * mu;
    const float rs = rsqrtf(var + 1e-5f);
    const float4 g = *(const float4*)&gam[lane * 4];
    const float4 b = *(const float4*)&bet[lane * 4];
    ushort4 o;
    o.x = f2b((v.x - mu) * rs * g.x + b.x);
    o.y = f2b((v.y - mu) * rs * g.y + b.y);
    o.z = f2b((v.z - mu) * rs * g.z + b.z);
    o.w = f2b((v.w - mu) * rs * g.w + b.w);
    *(ushort4*)&out[row * 256 + lane * 4] = o;
}

// ---------------- TT gemm + fused LN2: 128x256 tile, 512 threads (proven R7 structure)
__global__ __launch_bounds__(512) void tt_ln2(const ushort_t* __restrict__ A,
                                              const ushort_t* __restrict__ Bt0,
                                              const ushort_t* __restrict__ Bt1,
                                              const float* __restrict__ g2,
                                              const float* __restrict__ be2,
                                              const float* __restrict__ entf,
                                              ushort_t* __restrict__ yn,
                                              ushort_t* __restrict__ xb) {
    __shared__ __attribute__((aligned(16))) ushort_t As[128 * 64];   // 16 KB
    __shared__ __attribute__((aligned(16))) ushort_t Bs[256 * 64];   // 32 KB
    __shared__ float red_s[128 * 4];
    __shared__ float red_q[128 * 4];

    const int t = threadIdx.x;
    const int m0 = blockIdx.x * 128;
    const int lane = t & 63;
    const int wave = t >> 6;
    const int wr = wave & 1, wc = wave >> 1;
    const int l16 = lane & 15, quad = lane >> 4;
    const int tr = t >> 3;
    const int csw = (((t & 7) ^ (tr & 7)) << 3);

    const ushort_t* Bt = (m0 >= M_SZ / 2) ? Bt1 : Bt0;

    f32x4 acc[4][4];
#pragma unroll
    for (int i = 0; i < 4; i++)
#pragma unroll
        for (int j = 0; j < 4; j++) acc[i][j] = (f32x4)(0.0f);

    for (int kt = 0; kt < 32; ++kt) {
        const int kg = kt * 64;
        __syncthreads();
#pragma unroll
        for (int p = 0; p < 2; ++p) {
            const int mrow = m0 + p * 64 + tr;
            const int kcol = kg + csw;
            const int s = kcol >> 8;
            const ushort_t* gA = A + (size_t)((mrow & ~7) + (((mrow & 7) - s) & 7)) * 256 + (kcol & 255);
            gl2lds16(gA, As + p * 4096 + t * 8);
        }
#pragma unroll
        for (int p = 0; p < 4; ++p) {
            gl2lds16(Bt + (size_t)(p * 64 + tr) * 2048 + kg + csw, Bs + p * 4096 + t * 8);
        }
        __syncthreads();

#pragma unroll
        for (int kk = 0; kk < 2; ++kk) {
            const int ac = ((((kk << 2) | quad) ^ (l16 & 7)) << 3);
            bf16x8 af[4], bfv[4];
#pragma unroll
            for (int i = 0; i < 4; i++) af[i]  = *(const bf16x8*)&As[(wr * 64 + i * 16 + l16) * 64 + ac];
#pragma unroll
            for (int j = 0; j < 4; j++) bfv[j] = *(const bf16x8*)&Bs[(wc * 64 + j * 16 + l16) * 64 + ac];
#pragma unroll
            for (int i = 0; i < 4; i++)
#pragma unroll
                for (int j = 0; j < 4; j++)
                    acc[i][j] = __builtin_amdgcn_mfma_f32_16x16x32_bf16(af[i], bfv[j], acc[i][j], 0, 0, 0);
        }
    }

    int c[4];
#pragma unroll
    for (int j = 0; j < 4; j++) c[j] = wc * 64 + j * 16 + l16;
#pragma unroll
    for (int i = 0; i < 4; i++) {
#pragma unroll
        for (int r = 0; r < 4; r++) {
            const int rl = wr * 64 + i * 16 + quad * 4 + r;
            const size_t grow = (size_t)(m0 + rl) * 256;
            float s = 0.0f, q = 0.0f;
#pragma unroll
            for (int j = 0; j < 4; j++) {
                float v = acc[i][j][r] + entf[grow + c[j]];
                acc[i][j][r] = v;
                s += v;
                q += v * v;
            }
#pragma unroll
            for (int off = 1; off < 16; off <<= 1) {
                s += __shfl_xor(s, off, 64);
                q += __shfl_xor(q, off, 64);
            }
            if (l16 == 0) { red_s[rl * 4 + wc] = s; red_q[rl * 4 + wc] = q; }
        }
    }
    __syncthreads();
#pragma unroll
    for (int i = 0; i < 4; i++) {
#pragma unroll
        for (int r = 0; r < 4; r++) {
            const int rl = wr * 64 + i * 16 + quad * 4 + r;
            const size_t grow = (size_t)(m0 + rl) * 256;
            const float4 ss = *(const float4*)&red_s[rl * 4];
            const float4 qq = *(const float4*)&red_q[rl * 4];
            const float S = ss.x + ss.y + ss.z + ss.w;
            const float Q = qq.x + qq.y + qq.z + qq.w;
            const float mu = S * (1.0f / 256.0f);
            const float var = Q * (1.0f / 256.0f) - mu * mu;
            const float rs = rsqrtf(var + 1e-5f);
#pragma unroll
            for (int j = 0; j < 4; j++) {
                const float v = acc[i][j][r];
                yn[grow + c[j]] = f2b((v - mu) * rs * g2[c[j]] + be2[c[j]]);
                xb[grow + c[j]] = f2b(v);
            }
        }
    }
}

// ---------------- fused FF1+FF2 with HARDENED Hc handoff.
// R8 failed post-timing (deterministic-on-warm divergence). The only window not
// explicitly barrier-bracketed was GEMM1's last MFMA/ds_reads vs the Hc ds_writes.
// R9 adds a full __syncthreads() between them, so every LDS producer/consumer
// pair is strictly bracketed: reads drained -> barrier -> Hc writes -> barrier ->
// DMA stage -> barrier -> Hc reads.
#define HSTRIDE 272   // 16B-aligned rows; (4q+r)*136dw %32 spreads quads -> conflict-free writes
__global__ __launch_bounds__(512) void ff_fused(const ushort_t* __restrict__ yn,
                                                const ushort_t* __restrict__ W1b,
                                                const ushort_t* __restrict__ W2b,
                                                const float* __restrict__ bias1,
                                                const float* __restrict__ bias2,
                                                const ushort_t* __restrict__ xb,
                                                float* __restrict__ out) {
    __shared__ __attribute__((aligned(16))) ushort_t As[128 * 64];      // 16 KB
    __shared__ __attribute__((aligned(16))) ushort_t Bs[256 * 64];      // 32 KB
    __shared__ __attribute__((aligned(16))) ushort_t Hc[128 * HSTRIDE]; // 68 KB

    const int t = threadIdx.x;
    const int m0 = blockIdx.x * 128;
    const int lane = t & 63;
    const int wave = t >> 6;
    const int wr = wave & 1, wc = wave >> 1;
    const int l16 = lane & 15, quad = lane >> 4;
    const int tr = t >> 3;
    const int csw = (((t & 7) ^ (tr & 7)) << 3);

    f32x4 acc2[4][4];
#pragma unroll
    for (int i = 0; i < 4; i++)
#pragma unroll
        for (int j = 0; j < 4; j++) acc2[i][j] = (f32x4)(0.0f);

    int c4[4];
#pragma unroll
    for (int j = 0; j < 4; j++) c4[j] = wc * 64 + j * 16 + l16;

    for (int c = 0; c < 8; ++c) {
        f32x4 acc1[4][4];
#pragma unroll
        for (int i = 0; i < 4; i++)
#pragma unroll
            for (int j = 0; j < 4; j++) acc1[i][j] = (f32x4)(0.0f);

        // ---- GEMM1: yn_tile[128x256] @ W1 rows [c*256, c*256+256)
        for (int kb = 0; kb < 4; ++kb) {
            const int kg = kb * 64;
            __syncthreads();
#pragma unroll
            for (int p = 0; p < 2; ++p) {
                gl2lds16(yn + (size_t)(m0 + p * 64 + tr) * 256 + kg + csw, As + p * 4096 + t * 8);
            }
#pragma unroll
            for (int p = 0; p < 4; ++p) {
                gl2lds16(W1b + (size_t)(c * 256 + p * 64 + tr) * 256 + kg + csw, Bs + p * 4096 + t * 8);
            }
            __syncthreads();
#pragma unroll
            for (int kk = 0; kk < 2; ++kk) {
                const int ac = ((((kk << 2) | quad) ^ (l16 & 7)) << 3);
                bf16x8 af[4], bfv[4];
#pragma unroll
                for (int i = 0; i < 4; i++) af[i]  = *(const bf16x8*)&As[(wr * 64 + i * 16 + l16) * 64 + ac];
#pragma unroll
                for (int j = 0; j < 4; j++) bfv[j] = *(const bf16x8*)&Bs[(wc * 64 + j * 16 + l16) * 64 + ac];
#pragma unroll
                for (int i = 0; i < 4; i++)
#pragma unroll
                    for (int j = 0; j < 4; j++)
                        acc1[i][j] = __builtin_amdgcn_mfma_f32_16x16x32_bf16(af[i], bfv[j], acc1[i][j], 0, 0, 0);
            }
        }

        __syncthreads();   // R9 hardening: all GEMM1 LDS reads complete before Hc writes begin

        // ---- bias1 + relu -> Hc (bf16, row-major [m][ff], stride HSTRIDE)
#pragma unroll
        for (int j = 0; j < 4; j++) {
            const float bb = bias1[c * 256 + c4[j]];
#pragma unroll
            for (int i = 0; i < 4; i++) {
                const int rbase = wr * 64 + i * 16 + quad * 4;
#pragma unroll
                for (int r = 0; r < 4; r++) {
                    float v = acc1[i][j][r] + bb;
                    v = v > 0.0f ? v : 0.0f;
                    Hc[(rbase + r) * HSTRIDE + c4[j]] = f2b(v);
                }
            }
        }

        // ---- GEMM2: acc2 += Hc[128x256] @ W2 cols [c*256, c*256+256)
        for (int kb = 0; kb < 4; ++kb) {
            __syncthreads();   // kb=0: Hc writes drained & visible; kb>0: Bs reads drained
#pragma unroll
            for (int p = 0; p < 4; ++p) {
                gl2lds16(W2b + (size_t)(p * 64 + tr) * 2048 + c * 256 + kb * 64 + csw, Bs + p * 4096 + t * 8);
            }
            __syncthreads();
#pragma unroll
            for (int kk = 0; kk < 2; ++kk) {
                const int ank = kb * 64 + (((kk << 2) | quad) << 3);          // natural (Hc)
                const int ac = ((((kk << 2) | quad) ^ (l16 & 7)) << 3);       // swizzled (Bs)
                bf16x8 af[4], bfv[4];
#pragma unroll
                for (int i = 0; i < 4; i++) af[i]  = *(const bf16x8*)&Hc[(wr * 64 + i * 16 + l16) * HSTRIDE + ank];
#pragma unroll
                for (int j = 0; j < 4; j++) bfv[j] = *(const bf16x8*)&Bs[(wc * 64 + j * 16 + l16) * 64 + ac];
#pragma unroll
                for (int i = 0; i < 4; i++)
#pragma unroll
                    for (int j = 0; j < 4; j++)
                        acc2[i][j] = __builtin_amdgcn_mfma_f32_16x16x32_bf16(af[i], bfv[j], acc2[i][j], 0, 0, 0);
            }
        }
    }

    // ---- epilogue: + bias2 + xb residual -> out (f32)
#pragma unroll
    for (int j = 0; j < 4; j++) {
        const float b2 = bias2[c4[j]];
#pragma unroll
        for (int i = 0; i < 4; i++) {
            const int rbase = m0 + wr * 64 + i * 16 + quad * 4;
#pragma unroll
            for (int r = 0; r < 4; r++) {
                const size_t o = (size_t)(rbase + r) * 256 + c4[j];
                out[o] = acc2[i][j][r] + b2 + b2f(xb[o]);
            }
        }
    }
}

extern "C" void kernel_launch(void* const* d_in, const int* in_sizes, int n_in,
                              void* d_out, int out_size, void* d_ws, size_t ws_size,
                              hipStream_t stream) {
    const float* ent   = (const float*)d_in[0];
    const float* w_in  = (const float*)d_in[1];
    const float* w_out = (const float*)d_in[2];
    const float* W1    = (const float*)d_in[3];
    const float* bias1 = (const float*)d_in[4];
    const float* W2    = (const float*)d_in[5];
    const float* bias2 = (const float*)d_in[6];
    const float* g1    = (const float*)d_in[7];
    const float* be1   = (const float*)d_in[8];
    const float* g2    = (const float*)d_in[9];
    const float* be2   = (const float*)d_in[10];
    float* out = (float*)d_out;

    char* ws = (char*)d_ws;
    ushort_t* xn     = (ushort_t*)ws;
    ushort_t* yn     = (ushort_t*)(ws + 16777216);
    ushort_t* xb     = (ushort_t*)(ws + 2 * 16777216);
    ushort_t* bt_in  = (ushort_t*)(ws + 3 * 16777216);
    ushort_t* bt_out = bt_in + WELEM;
    ushort_t* W1b    = bt_out + WELEM;
    ushort_t* W2b    = W1b + WELEM;

    // 1) convert + repack weights to bf16
    convert_weights<<<dim3(768), dim3(256), 0, stream>>>(w_in, w_out, W1, W2,
                                                         bt_in, bt_out, W1b, W2b);
    // 2) LN1: ent -> xn (bf16)
    ln_fast<<<dim3(M_SZ / 4), dim3(256), 0, stream>>>(ent, g1, be1, xn);
    // 3) TT gemm + fused LN2: yn, xb
    tt_ln2<<<dim3(M_SZ / 128), dim3(512), 0, stream>>>(xn, bt_in, bt_out, g2, be2, ent, yn, xb);
    // 4) fused FF1+FF2: out = xb + relu(yn@W1^T+b1)@W2^T + b2
    ff_fused<<<dim3(M_SZ / 128), dim3(512), 0, stream>>>(yn, W1b, W2b, bias1, bias2, xb, out);
}